// Round 19
// baseline (371.350 us; speedup 1.0000x reference)
//
#include <hip/hip_runtime.h>

typedef _Float16 f16;
typedef _Float16 f16x8 __attribute__((ext_vector_type(8)));
typedef _Float16 f16x4 __attribute__((ext_vector_type(4)));
typedef float f32x4 __attribute__((ext_vector_type(4)));

__device__ __forceinline__ void gload16(const void* g, void* l) {
  __builtin_amdgcn_global_load_lds(
      (const __attribute__((address_space(1))) void*)g,
      (__attribute__((address_space(3))) void*)l, 16, 0, 0);
}

#define SCHED_FENCE __builtin_amdgcn_sched_barrier(0)
#define RAW_BARRIER do { SCHED_FENCE; __builtin_amdgcn_s_barrier(); SCHED_FENCE; } while (0)
#define WAIT_VM_0    do { asm volatile("s_waitcnt vmcnt(0)"     ::: "memory"); SCHED_FENCE; } while (0)
#define WAIT_VM_4    do { asm volatile("s_waitcnt vmcnt(4)"     ::: "memory"); SCHED_FENCE; } while (0)
#define WAIT_VM_8    do { asm volatile("s_waitcnt vmcnt(8)"     ::: "memory"); SCHED_FENCE; } while (0)
#define WAIT_LGKM_0  do { asm volatile("s_waitcnt lgkmcnt(0)"   ::: "memory"); SCHED_FENCE; } while (0)
#define WAIT_LGKM_11 do { asm volatile("s_waitcnt lgkmcnt(11)"  ::: "memory"); SCHED_FENCE; } while (0)

// ============ qkv GEMM: frozen R7 body; LDS-staged d-major norms (stride-132 padded) ======
__global__ __launch_bounds__(512, 2)
void gemm256_qkv(const f16* __restrict__ A, const f16* __restrict__ B,
                 f16* __restrict__ CT, const float* __restrict__ bias,
                 float* __restrict__ nqT, float* __restrict__ nkT)
{
  __shared__ f16 lds[4 * 14336];
  const int s = blockIdx.x;
  const int tile = (s & 7) * 64 + (s >> 3);
  const int brow = (tile >> 4) << 8;
  const int bcol = (tile & 15) * 192;
  const int NT = 32;
  const int tid = threadIdx.x;
  const int lane = tid & 63;
  const int wid = tid >> 6;
  const int wr = wid >> 2;
  const int wc = wid & 3;
  const int fr = lane & 15;
  const int kq = lane >> 4;

  const f16* pA[2]; const f16* pB[2]; int pdA[2], pdB[2];
#pragma unroll
  for (int i = 0; i < 2; i++) {
    const int p = wid * 128 + i * 64 + lane;
    const int rr = ((p >> 6) << 4) | ((p >> 2) & 15);
    const int c4 = (p & 3) ^ ((p >> 3) & 3);
    pA[i] = A + (long)(brow + rr) * 1024 + c4 * 8;
    pdA[i] = p * 8;
    const int g = (p >= 768) ? p - 256 : p;
    const int rb = ((g >> 6) << 4) | ((g >> 2) & 15);
    const int cb = (g & 3) ^ ((g >> 3) & 3);
    pB[i] = B + (long)(bcol + rb) * 1024 + cb * 8;
    pdB[i] = 8192 + g * 8;
  }

  auto STAGE = [&](int t) {
    f16* base = lds + (t & 3) * 14336;
    const int off = t * 32;
#pragma unroll
    for (int i = 0; i < 2; i++) {
      gload16(pA[i] + off, base + pdA[i]);
      gload16(pB[i] + off, base + pdB[i]);
    }
  };

  const int aoff0 = fr * 4 + (kq ^ ((fr >> 1) & 3));
  f32x4 acc[8][3] = {};
  f16x8 avA[8], bvA[3], avB[8], bvB[3];

  STAGE(0); STAGE(1); STAGE(2);
  WAIT_VM_4;
  RAW_BARRIER;
#pragma unroll
  for (int m = 0; m < 8; m++)
    avA[m] = *(const f16x8*)(lds + ((wr * 8 + m) * 64 + aoff0) * 8);
#pragma unroll
  for (int n = 0; n < 3; n++)
    bvA[n] = *(const f16x8*)(lds + 8192 + ((wc * 3 + n) * 64 + aoff0) * 8);

#define GEMM_ITER(T, AVC, BVC, AVN, BVN)                                        \
  do {                                                                          \
    if ((T) + 3 < NT) STAGE((T) + 3);                                           \
    if ((T) + 1 < NT) {                                                         \
      const f16* nb_ = lds + (((T) + 1) & 3) * 14336;                           \
      _Pragma("unroll")                                                         \
      for (int m = 0; m < 8; m++)                                               \
        AVN[m] = *(const f16x8*)(nb_ + ((wr * 8 + m) * 64 + aoff0) * 8);        \
      _Pragma("unroll")                                                         \
      for (int n = 0; n < 3; n++)                                               \
        BVN[n] = *(const f16x8*)(nb_ + 8192 + ((wc * 3 + n) * 64 + aoff0) * 8); \
      WAIT_LGKM_11;                                                             \
    } else {                                                                    \
      WAIT_LGKM_0;                                                              \
    }                                                                           \
    __builtin_amdgcn_s_setprio(1);                                              \
    _Pragma("unroll")                                                           \
    for (int m = 0; m < 8; m++)                                                 \
      _Pragma("unroll")                                                         \
      for (int n = 0; n < 3; n++)                                               \
        acc[m][n] = __builtin_amdgcn_mfma_f32_16x16x32_f16(AVC[m], BVC[n],      \
                                                           acc[m][n], 0, 0, 0); \
    __builtin_amdgcn_s_setprio(0);                                              \
    if ((T) + 3 < NT)      { WAIT_VM_4; }                                       \
    else if ((T) + 2 < NT) { WAIT_VM_0; }                                       \
    RAW_BARRIER;                                                                \
  } while (0)

#pragma unroll 1
  for (int t = 0; t < NT; t += 2) {
    GEMM_ITER(t,     avA, bvA, avB, bvB);
    GEMM_ITER(t + 1, avB, bvB, avA, bvA);
  }
#undef GEMM_ITER

  float* nlds = (float*)lds;   // 96 x (stride 132) f32 tile; LDS dead after K-loop
#pragma unroll
  for (int m = 0; m < 8; m++) {
    const int row0 = brow + wr * 128 + m * 16 + kq * 4;
    const int bI = row0 >> 11, srow = row0 & 2047;
#pragma unroll
    for (int n = 0; n < 3; n++) {
      const int col = bcol + wc * 48 + n * 16 + fr;
      const float bb = bias[col];
      const float v0 = acc[m][n][0] + bb, v1 = acc[m][n][1] + bb;
      const float v2 = acc[m][n][2] + bb, v3 = acc[m][n][3] + bb;
      f16x4 w = {(f16)v0, (f16)v1, (f16)v2, (f16)v3};
      *(f16x4*)&CT[((long)bI * 3072 + col) * 2048 + srow] = w;
      const int tcol = bcol + wc * 48 + n * 16;
      if (tcol < 2048) {
        float h0 = v0 * v0 + v1 * v1;
        float h1 = v2 * v2 + v3 * v3;
        h0 += __shfl_xor(h0, 1, 64);
        h1 += __shfl_xor(h1, 1, 64);
        if (!(lane & 1)) {
          const int d2l = (wc * 48 + n * 16 + fr) >> 1;
          const int s2l = (wr * 128 + m * 16 + kq * 4) >> 1;
          nlds[d2l * 132 + s2l]     = h0;
          nlds[d2l * 132 + s2l + 1] = h1;
        }
      }
    }
  }
  if (bcol < 2048) {
    __syncthreads();
    const int bI = brow >> 11;
    const int s2b = (brow & 2047) >> 1;
    for (int i = tid; i < 96 * 64; i += 512) {
      const int r = i >> 6, c2 = i & 63;
      const int col = bcol + 2 * r;
      if (col < 2048) {
        const int tau = col >> 10;
        float* dst = (tau ? nkT : nqT)
                   + ((long)bI * 512 + ((col & 1023) >> 1)) * 1024 + s2b + c2 * 2;
        *(float2*)dst = *(float2*)&nlds[r * 132 + c2 * 2];
      }
    }
  }
}

// ============ 128x128 GEMM body: BK=64 hi-occupancy (32KB LDS), R16-verified ==============
template<typename OutT, bool TRANSC>
__device__ __forceinline__ void gemm_body_hi64(
    const f16* __restrict__ A, const f16* __restrict__ B, OutT* __restrict__ C,
    int K, int lda, int ldb, int ldc, float alpha,
    f16* lA, f16* lB, int brow, int bcol)
{
  const int tid = threadIdx.x;
  const int lane = tid & 63;
  const int wid = tid >> 6;
  const int wr = (wid >> 1) << 6;
  const int wc = (wid & 1) << 6;
  const int fr = lane & 15;
  const int kq = lane >> 4;

  const f16* gA = A + (long)brow * lda;
  const f16* gB = B + (long)bcol * ldb;
  int offA[4], offB[4], pd[4];
#pragma unroll
  for (int i = 0; i < 4; i++) {
    const int p = i * 256 + tid;
    const int r = p >> 3;
    const int c8 = (p & 7) ^ (r & 7);
    offA[i] = r * lda + c8 * 8;
    offB[i] = r * ldb + c8 * 8;
    pd[i] = p * 8;
  }

  f32x4 acc[4][4] = {};

  for (int t = 0; t < K; t += 64) {
#pragma unroll
    for (int i = 0; i < 4; i++) gload16(gA + offA[i] + t, lA + pd[i]);
#pragma unroll
    for (int i = 0; i < 4; i++) gload16(gB + offB[i] + t, lB + pd[i]);
    __syncthreads();
#pragma unroll
    for (int h = 0; h < 2; h++) {
      const int c8a = h * 4 + kq;
      f16x8 av[4], bv[4];
#pragma unroll
      for (int m = 0; m < 4; m++) {
        const int r = wr + m * 16 + fr;
        av[m] = *(const f16x8*)&lA[(r * 8 + (c8a ^ (r & 7))) * 8];
      }
#pragma unroll
      for (int n = 0; n < 4; n++) {
        const int r = wc + n * 16 + fr;
        bv[n] = *(const f16x8*)&lB[(r * 8 + (c8a ^ (r & 7))) * 8];
      }
#pragma unroll
      for (int m = 0; m < 4; m++)
#pragma unroll
        for (int n = 0; n < 4; n++)
          acc[m][n] = __builtin_amdgcn_mfma_f32_16x16x32_f16(av[m], bv[n], acc[m][n], 0, 0, 0);
    }
    __syncthreads();
  }

#pragma unroll
  for (int m = 0; m < 4; m++)
#pragma unroll
    for (int n = 0; n < 4; n++) {
      const int row0 = brow + wr + m * 16 + kq * 4;
      const int col  = bcol + wc + n * 16 + fr;
      if constexpr (TRANSC) {
        f16x4 v;
#pragma unroll
        for (int i = 0; i < 4; i++) v[i] = (f16)(acc[m][n][i] * alpha);
        *(f16x4*)&C[(long)col * ldc + row0] = v;
      } else {
#pragma unroll
        for (int i = 0; i < 4; i++)
          C[(long)(row0 + i) * ldc + col] = (OutT)(acc[m][n][i] * alpha);
      }
    }
}

// ============ 128x128 GEMM body: 4-buf deep pipeline (for 1-blk/CU grids), R16-verified ===
template<typename OutT, bool TRANSC>
__device__ __forceinline__ void gemm_body_pipe(
    const f16* __restrict__ A, const f16* __restrict__ B, OutT* __restrict__ C,
    int K, int lda, int ldb, int ldc, float alpha, f16* lds, int brow, int bcol)
{
  const int NT = K >> 5;
  const int tid = threadIdx.x;
  const int lane = tid & 63;
  const int wid = tid >> 6;
  const int wr = (wid >> 1) << 6;
  const int wc = (wid & 1) << 6;
  const int fr = lane & 15;
  const int kq = lane >> 4;
  const int kqsw = kq ^ ((fr >> 1) & 3);

  const int srow = tid >> 2;
  const int skq  = (tid & 3) ^ ((tid >> 3) & 3);
  const f16* gA0 = A + (long)(brow + srow) * lda + skq * 8;
  const f16* gA1 = A + (long)(brow + 64 + srow) * lda + skq * 8;
  const f16* gB0 = B + (long)(bcol + srow) * ldb + skq * 8;
  const f16* gB1 = B + (long)(bcol + 64 + srow) * ldb + skq * 8;
  const int dA0 = tid * 8, dA1 = 2048 + tid * 8;
  const int dB0 = 4096 + tid * 8, dB1 = 6144 + tid * 8;

  auto STAGE = [&](int t) {
    f16* base = lds + (t & 3) * 8192;
    const int off = t * 32;
    gload16(gA0 + off, base + dA0);
    gload16(gA1 + off, base + dA1);
    gload16(gB0 + off, base + dB0);
    gload16(gB1 + off, base + dB1);
  };

  f32x4 acc[4][4] = {};

  STAGE(0); STAGE(1); STAGE(2);
  WAIT_VM_8;
  RAW_BARRIER;

#pragma unroll 1
  for (int t = 0; t < NT; ++t) {
    if (t + 3 < NT) STAGE(t + 3);
    SCHED_FENCE;
    const f16* base = lds + (t & 3) * 8192;
    f16x8 av[4], bv[4];
#pragma unroll
    for (int m = 0; m < 4; m++)
      av[m] = *(const f16x8*)(base + (wr + m * 16 + fr) * 32 + kqsw * 8);
#pragma unroll
    for (int n = 0; n < 4; n++)
      bv[n] = *(const f16x8*)(base + 4096 + (wc + n * 16 + fr) * 32 + kqsw * 8);
    __builtin_amdgcn_s_setprio(1);
#pragma unroll
    for (int m = 0; m < 4; m++)
#pragma unroll
      for (int n = 0; n < 4; n++)
        acc[m][n] = __builtin_amdgcn_mfma_f32_16x16x32_f16(av[m], bv[n], acc[m][n], 0, 0, 0);
    __builtin_amdgcn_s_setprio(0);
    if (t + 1 < NT) {
      WAIT_LGKM_0;
      if (t + 3 < NT)      { WAIT_VM_8; }
      else if (t + 2 < NT) { WAIT_VM_4; }
      else                 { WAIT_VM_0; }
      RAW_BARRIER;
    }
  }

#pragma unroll
  for (int m = 0; m < 4; m++)
#pragma unroll
    for (int n = 0; n < 4; n++) {
      const int row0 = brow + wr + m * 16 + kq * 4;
      const int col  = bcol + wc + n * 16 + fr;
      if constexpr (TRANSC) {
        f16x4 v;
#pragma unroll
        for (int i = 0; i < 4; i++) v[i] = (f16)(acc[m][n][i] * alpha);
        *(f16x4*)&C[(long)col * ldc + row0] = v;
      } else {
#pragma unroll
        for (int i = 0; i < 4; i++)
          C[(long)(row0 + i) * ldc + col] = (OutT)(acc[m][n][i] * alpha);
      }
    }
}

// L1 (512 hi64, XCD swz): z<4 -> B2n_b = x^T.v /32 ; else Zt_b = x^T.WO_ /32
__global__ __launch_bounds__(256)
void gemmL1(const f16* __restrict__ xT, const f16* __restrict__ qkvT,
            const f16* __restrict__ WOT, f16* __restrict__ B2n, f16* __restrict__ Zt)
{
  __shared__ f16 lA[8192];
  __shared__ f16 lB[8192];
  const int s = blockIdx.x;
  const int tile = (s & 7) * 64 + (s >> 3);
  const int z = tile >> 6, rem = tile & 63;
  const int brow = (rem >> 3) << 7, bcol = (rem & 7) << 7;
  const int b = z & 3;
  const f16* A = xT + (long)b * 1024 * 2048;
  const f16* B; f16* C;
  if (z < 4) { B = qkvT + (long)b * 3072 * 2048 + 2048L * 2048; C = B2n + (long)b * 1024 * 1024; }
  else       { B = WOT + (long)b * 1024 * 2048;                 C = Zt  + (long)b * 1024 * 1024; }
  gemm_body_hi64<f16, false>(A, B, C, 2048, 2048, 2048, 1024, 0.03125f, lA, lB, brow, bcol);
}

// L2 (512 hi64, XCD swz): z<4 -> A1_b = Pq^T.Pk /32 (direct from masked qkvT); else PT_b
__global__ __launch_bounds__(256)
void gemmL2(const f16* __restrict__ qkvT, f16* __restrict__ A1,
            const f16* __restrict__ B2n, const f16* __restrict__ Zt, f16* __restrict__ PT)
{
  __shared__ f16 lA[8192];
  __shared__ f16 lB[8192];
  const int s = blockIdx.x;
  const int tile = (s & 7) * 64 + (s >> 3);
  const int z = tile >> 6, rem = tile & 63;
  const int brow = (rem >> 3) << 7, bcol = (rem & 7) << 7;
  const int b = z & 3;
  if (z < 4) {
    const f16* q = qkvT + (long)b * 3072 * 2048;
    const f16* k = qkvT + (long)b * 3072 * 2048 + 1024L * 2048;
    gemm_body_hi64<f16, false>(q, k, A1 + (long)b * 1024 * 1024,
                               2048, 2048, 2048, 1024, 0.03125f, lA, lB, brow, bcol);
  } else {
    gemm_body_hi64<f16, true>(B2n + (long)b * 1024 * 1024, Zt + (long)b * 1024 * 1024,
                              PT + (long)b * 1024 * 1024,
                              1024, 1024, 1024, 1024, 0.25f, lA, lB, brow, bcol);
  }
}

// L3 (256 pipe, XCD swz): M2T_b = (A1.P)^T
__global__ __launch_bounds__(256)
void gemmL3(const f16* __restrict__ A1, const f16* __restrict__ PT, f16* __restrict__ M2T)
{
  __shared__ f16 lds[32768];
  const int s = blockIdx.x;
  const int tile = (s & 7) * 32 + (s >> 3);
  const int b = tile >> 6, rem = tile & 63;
  gemm_body_pipe<f16, true>(A1 + (long)b * 1024 * 1024, PT + (long)b * 1024 * 1024,
                            M2T + (long)b * 1024 * 1024,
                            1024, 1024, 1024, 1024, 1.f, lds,
                            (rem >> 3) << 7, (rem & 7) << 7);
}

// L4 (512 hi64, XCD swz): out_b = x.M2 * 4096
__global__ __launch_bounds__(256)
void gemmL4(const f16* __restrict__ xh, const f16* __restrict__ M2T, float* __restrict__ out)
{
  __shared__ f16 lA[8192];
  __shared__ f16 lB[8192];
  const int s = blockIdx.x;
  const int tile = (s & 7) * 64 + (s >> 3);
  const int b = tile >> 7, rem = tile & 127;
  gemm_body_hi64<float, false>(xh + (long)b * 2048 * 1024, M2T + (long)b * 1024 * 1024,
                               out + (long)b * 2048 * 1024,
                               1024, 1024, 1024, 1024, 4096.f, lA, lB,
                               (rem >> 3) << 7, (rem & 7) << 7);
}

// ---------------- cvt combo: z<8192 x->(xh,xT); z<11264 Wqkv->wh;
//                  z<13312 WO row-norms + WO->woh f16; else select_init (+done counters)
__global__ __launch_bounds__(256)
void cvt_combo(const float* __restrict__ x, f16* __restrict__ xh, f16* __restrict__ xT,
               const float* __restrict__ Wqkv, f16* __restrict__ wh,
               const float* __restrict__ WO, float* __restrict__ wno, f16* __restrict__ woh,
               unsigned* __restrict__ hist, unsigned* __restrict__ prefix,
               unsigned* __restrict__ rankrem, unsigned* __restrict__ cnt) {
  const int z = blockIdx.x;
  const int tid = threadIdx.x;
  if (z < 8192) {
    __shared__ f16 t[32][33];
    const int b = z >> 11, r = z & 2047;
    const int s0 = (r & 63) * 32, d0 = (r >> 6) * 32;
    const int tx = tid & 31, ty = tid >> 5;
#pragma unroll
    for (int j = 0; j < 32; j += 8) {
      const long idx = ((long)b * 2048 + s0 + ty + j) * 1024 + d0 + tx;
      f16 h = (f16)x[idx];
      xh[idx] = h;
      t[ty + j][tx] = h;
    }
    __syncthreads();
#pragma unroll
    for (int j = 0; j < 32; j += 8)
      xT[((long)b * 1024 + d0 + ty + j) * 2048 + s0 + tx] = t[tx][ty + j];
  } else if (z < 11264) {
    const long i = (long)(z - 8192) * 256 + tid;
    float4 v = ((const float4*)Wqkv)[i];
    f16x4 o = {(f16)v.x, (f16)v.y, (f16)v.z, (f16)v.w};
    ((f16x4*)wh)[i] = o;
  } else if (z < 13312) {
    const int wid = tid >> 6, lane = tid & 63;
    const long row = (long)(z - 11264) * 4 + wid;
    const float* p = WO + row * 1024;
    float s = 0.f;
#pragma unroll
    for (int j = 0; j < 4; j++) {
      float4 v = *(const float4*)(p + lane * 4 + j * 256);
      s += v.x*v.x + v.y*v.y + v.z*v.z + v.w*v.w;
      f16x4 o = {(f16)v.x, (f16)v.y, (f16)v.z, (f16)v.w};
      *(f16x4*)(woh + row * 1024 + lane * 4 + j * 256) = o;
    }
    for (int off = 32; off; off >>= 1) s += __shfl_down(s, off, 64);
    if (lane == 0) wno[row] = s;
  } else {
    const int i = (z - 13312) * 256 + tid;
    if (i < 12 * 4096) hist[i] = 0;
    if (i < 12) { prefix[i] = 0; rankrem[i] = (i < 8) ? 262144u : 1024u; }
    if (i >= 12 && i < 44) cnt[i - 12] = 0;   // 32 done-counters (2 passes x 16 slots)
  }
}

// ---------------- fused hist+scan: grid (32,12); last block per pid runs the scan.
// Device-scope atomics + __threadfence release/acquire around a per-pid done counter
// (no dispatch-order assumption; G12/G16-compliant). Scan logic identical to before.
__global__ __launch_bounds__(256)
void hist_scan(const float* __restrict__ nqT, const float* __restrict__ nkT,
               const float* __restrict__ wno, unsigned* __restrict__ hist,
               unsigned* __restrict__ prefix, unsigned* __restrict__ rankrem,
               float* __restrict__ thr, unsigned* __restrict__ cnt,
               int shift, int nbins, unsigned himask, int pass, int final_pass) {
  __shared__ unsigned lh[4096];
  const int pid = blockIdx.y;
  const int tid = threadIdx.x;
  for (int i = tid; i < nbins; i += 256) lh[i] = 0;
  __syncthreads();
  const float* base; long N;
  if (pid < 4)      { base = nqT + (long)pid       * 524288; N = 524288; }
  else if (pid < 8) { base = nkT + (long)(pid - 4) * 524288; N = 524288; }
  else              { base = wno + (long)(pid - 8) * 2048;   N = 2048;  }
  const unsigned pref = prefix[pid];
  long chunk = (N + gridDim.x - 1) / gridDim.x;
  long s = (long)blockIdx.x * chunk;
  long e = s + chunk; if (e > N) e = N;
  for (long i = s + tid; i < e; i += 256) {
    unsigned u = __float_as_uint(base[i]);
    if ((u & himask) == pref) atomicAdd(&lh[(u >> shift) & (nbins - 1)], 1u);
  }
  __syncthreads();
  unsigned* h = hist + pid * 4096;
  for (int i = tid; i < nbins; i += 256)
    if (lh[i]) atomicAdd(&h[i], lh[i]);

  // ---- completion protocol ----
  __threadfence();                      // release: my hist atomics visible device-wide
  __shared__ unsigned isLast;
  if (tid == 0)
    isLast = (atomicAdd(&cnt[pass * 16 + pid], 1u) == gridDim.x - 1) ? 1u : 0u;
  __syncthreads();
  if (!isLast) return;
  __threadfence();                      // acquire: all blocks' hist atomics visible

  // ---- scan (identical logic to scan_pass) ----
  const int per = nbins >> 8;           // 16
  const unsigned r = rankrem[pid];
  const unsigned oldpref = prefix[pid];
  unsigned local[16];
  unsigned sacc = 0;
#pragma unroll
  for (int j = 0; j < 16; j++) {
    if (j < per) {
      local[j] = h[tid * per + j];
      h[tid * per + j] = 0;             // re-zero for next pass
      sacc += local[j];
    }
  }
  __shared__ unsigned buf[2][256];
  buf[0][tid] = sacc;
  __syncthreads();
  int src = 0;
#pragma unroll
  for (int d = 1; d < 256; d <<= 1) {
    unsigned v = buf[src][tid];
    if (tid >= d) v += buf[src][tid - d];
    buf[src ^ 1][tid] = v;
    __syncthreads();
    src ^= 1;
  }
  const unsigned incl = buf[src][tid];
  const unsigned excl = incl - sacc;
  if (excl <= r && r < incl) {
    unsigned accu = excl;
#pragma unroll
    for (int j = 0; j < 16; j++) {
      if (j < per) {
        if (accu + local[j] > r) {
          rankrem[pid] = r - accu;
          unsigned np = oldpref | ((unsigned)(tid * per + j) << shift);
          prefix[pid] = np;
          if (final_pass) thr[pid] = __uint_as_float(np);
          break;
        }
        accu += local[j];
      }
    }
  }
}

// ---------------- mask combo: z<8192 in-place q/k zeroing; else WOT from woh (f16)
__global__ __launch_bounds__(256)
void mask_combo(f16* __restrict__ qkvT, const float* __restrict__ nqT,
                const float* __restrict__ nkT, const float* __restrict__ thr,
                const f16* __restrict__ woh, const float* __restrict__ wno,
                f16* __restrict__ WOT) {
  const int z = blockIdx.x;
  const int tid = threadIdx.x;
  if (z < 8192) {
    const int d  = z & 1023;
    const int tau = (z >> 10) & 1;
    const int bI = z >> 11;
    const float t = thr[tau * 4 + bI];
    const float4 nv = *(const float4*)((tau ? nkT : nqT)
                       + ((long)bI * 512 + (d >> 1)) * 1024 + tid * 4);
    unsigned* pb = (unsigned*)(qkvT + ((long)bI * 3072 + tau * 1024 + d) * 2048 + tid * 8);
    if (nv.x < t) pb[0] = 0u;
    if (nv.y < t) pb[1] = 0u;
    if (nv.z < t) pb[2] = 0u;
    if (nv.w < t) pb[3] = 0u;
  } else {
    __shared__ f16 t[32][33];
    const int zz = z - 8192;
    const int b = zz >> 11, r = zz & 2047;
    const int s0 = (r & 63) * 32, d0 = (r >> 6) * 32;
    const int tx = tid & 31, ty = tid >> 5;
    const float tb = thr[8 + b];
#pragma unroll
    for (int j = 0; j < 32; j += 8) {
      const int s = s0 + ty + j;
      const bool keep = wno[(long)b * 2048 + s] >= tb;
      t[ty + j][tx] = keep ? woh[((long)b * 2048 + s) * 1024 + d0 + tx] : (f16)0.f;
    }
    __syncthreads();
#pragma unroll
    for (int j = 0; j < 32; j += 8)
      WOT[((long)b * 1024 + d0 + ty + j) * 2048 + s0 + tx] = t[tx][ty + j];
  }
}

extern "C" void kernel_launch(void* const* d_in, const int* in_sizes, int n_in,
                              void* d_out, int out_size, void* d_ws, size_t ws_size,
                              hipStream_t stream) {
  const float* x    = (const float*)d_in[0];
  const float* Wqkv = (const float*)d_in[1];
  const float* bqkv = (const float*)d_in[2];
  const float* WO   = (const float*)d_in[3];
  float* out = (float*)d_out;

  char* w = (char*)d_ws;
  auto alloc = [&](size_t bytes) { char* p = w; w += (bytes + 255) & ~(size_t)255; return p; };
  f16*      xh      = (f16*)alloc(8192L * 1024 * 2);
  f16*      wh      = (f16*)alloc(3072L * 1024 * 2);
  f16*      xT      = (f16*)alloc(4L * 1024 * 2048 * 2);
  f16*      qkvT    = (f16*)alloc(4L * 3072 * 2048 * 2);
  float*    nqT     = (float*)alloc(4L * 524288 * 4);
  float*    nkT     = (float*)alloc(4L * 524288 * 4);
  float*    wno     = (float*)alloc(8192L * 4);
  f16*      woh     = (f16*)alloc(8192L * 1024 * 2);
  unsigned* hist    = (unsigned*)alloc(12L * 4096 * 4);
  unsigned* prefix  = (unsigned*)alloc(256);
  unsigned* rankrem = (unsigned*)alloc(256);
  float*    thr     = (float*)alloc(256);
  unsigned* cnt     = (unsigned*)alloc(256);
  f16*      WOT     = (f16*)alloc(4L * 1024 * 2048 * 2);
  f16*      B2n     = (f16*)alloc(4L * 1024 * 1024 * 2);
  f16*      Zt      = (f16*)alloc(4L * 1024 * 1024 * 2);
  f16*      A1      = (f16*)alloc(4L * 1024 * 1024 * 2);
  f16*      PT      = (f16*)alloc(4L * 1024 * 1024 * 2);
  f16*      M2T     = (f16*)alloc(4L * 1024 * 1024 * 2);
  if ((size_t)(w - (char*)d_ws) > ws_size) return;

  // 1. conversions + WO norms/f16 + select-init (+counter zeroing)
  cvt_combo<<<13504, 256, 0, stream>>>(x, xh, xT, Wqkv, wh, WO, wno, woh,
                                       hist, prefix, rankrem, cnt);
  // 2. qkv GEMM (frozen body) -> qkvT + LDS-staged d-major tile-norms (padded)
  gemm256_qkv<<<512, 512, 0, stream>>>(xh, wh, qkvT, bqkv, nqT, nkT);
  // 3. medians via 2 fused hist+scan passes (last-block-scans; 2 launches instead of 4)
  hist_scan<<<dim3(32, 12), 256, 0, stream>>>(nqT, nkT, wno, hist, prefix, rankrem, thr,
                                              cnt, 20, 4096, 0u, 0, 0);
  hist_scan<<<dim3(32, 12), 256, 0, stream>>>(nqT, nkT, wno, hist, prefix, rankrem, thr,
                                              cnt, 8, 4096, 0xFFF00000u, 1, 1);
  // 4. masks: in-place q/k zeroing + WOT from f16 woh
  mask_combo<<<16384, 256, 0, stream>>>(qkvT, nqT, nkT, thr, woh, wno, WOT);
  // 5. chain (R18-best assignment, fully XCD-swizzled)
  gemmL1<<<512, 256, 0, stream>>>(xT, qkvT, WOT, B2n, Zt);
  gemmL2<<<512, 256, 0, stream>>>(qkvT, A1, B2n, Zt, PT);
  gemmL3<<<256, 256, 0, stream>>>(A1, PT, M2T);
  gemmL4<<<512, 256, 0, stream>>>(xh, M2T, out);
}

// Round 20
// 315.526 us; speedup vs baseline: 1.1769x; 1.1769x over previous
//
#include <hip/hip_runtime.h>

typedef _Float16 f16;
typedef _Float16 f16x8 __attribute__((ext_vector_type(8)));
typedef _Float16 f16x4 __attribute__((ext_vector_type(4)));
typedef float f32x4 __attribute__((ext_vector_type(4)));

__device__ __forceinline__ void gload16(const void* g, void* l) {
  __builtin_amdgcn_global_load_lds(
      (const __attribute__((address_space(1))) void*)g,
      (__attribute__((address_space(3))) void*)l, 16, 0, 0);
}

#define SCHED_FENCE __builtin_amdgcn_sched_barrier(0)
#define RAW_BARRIER do { SCHED_FENCE; __builtin_amdgcn_s_barrier(); SCHED_FENCE; } while (0)
#define WAIT_VM_0    do { asm volatile("s_waitcnt vmcnt(0)"     ::: "memory"); SCHED_FENCE; } while (0)
#define WAIT_VM_4    do { asm volatile("s_waitcnt vmcnt(4)"     ::: "memory"); SCHED_FENCE; } while (0)
#define WAIT_VM_8    do { asm volatile("s_waitcnt vmcnt(8)"     ::: "memory"); SCHED_FENCE; } while (0)
#define WAIT_LGKM_0  do { asm volatile("s_waitcnt lgkmcnt(0)"   ::: "memory"); SCHED_FENCE; } while (0)
#define WAIT_LGKM_11 do { asm volatile("s_waitcnt lgkmcnt(11)"  ::: "memory"); SCHED_FENCE; } while (0)

// ============ qkv GEMM: frozen R7 body; LDS-staged d-major norms (stride-132 padded) ======
__global__ __launch_bounds__(512, 2)
void gemm256_qkv(const f16* __restrict__ A, const f16* __restrict__ B,
                 f16* __restrict__ CT, const float* __restrict__ bias,
                 float* __restrict__ nqT, float* __restrict__ nkT)
{
  __shared__ f16 lds[4 * 14336];
  const int s = blockIdx.x;
  const int tile = (s & 7) * 64 + (s >> 3);
  const int brow = (tile >> 4) << 8;
  const int bcol = (tile & 15) * 192;
  const int NT = 32;
  const int tid = threadIdx.x;
  const int lane = tid & 63;
  const int wid = tid >> 6;
  const int wr = wid >> 2;
  const int wc = wid & 3;
  const int fr = lane & 15;
  const int kq = lane >> 4;

  const f16* pA[2]; const f16* pB[2]; int pdA[2], pdB[2];
#pragma unroll
  for (int i = 0; i < 2; i++) {
    const int p = wid * 128 + i * 64 + lane;
    const int rr = ((p >> 6) << 4) | ((p >> 2) & 15);
    const int c4 = (p & 3) ^ ((p >> 3) & 3);
    pA[i] = A + (long)(brow + rr) * 1024 + c4 * 8;
    pdA[i] = p * 8;
    const int g = (p >= 768) ? p - 256 : p;
    const int rb = ((g >> 6) << 4) | ((g >> 2) & 15);
    const int cb = (g & 3) ^ ((g >> 3) & 3);
    pB[i] = B + (long)(bcol + rb) * 1024 + cb * 8;
    pdB[i] = 8192 + g * 8;
  }

  auto STAGE = [&](int t) {
    f16* base = lds + (t & 3) * 14336;
    const int off = t * 32;
#pragma unroll
    for (int i = 0; i < 2; i++) {
      gload16(pA[i] + off, base + pdA[i]);
      gload16(pB[i] + off, base + pdB[i]);
    }
  };

  const int aoff0 = fr * 4 + (kq ^ ((fr >> 1) & 3));
  f32x4 acc[8][3] = {};
  f16x8 avA[8], bvA[3], avB[8], bvB[3];

  STAGE(0); STAGE(1); STAGE(2);
  WAIT_VM_4;
  RAW_BARRIER;
#pragma unroll
  for (int m = 0; m < 8; m++)
    avA[m] = *(const f16x8*)(lds + ((wr * 8 + m) * 64 + aoff0) * 8);
#pragma unroll
  for (int n = 0; n < 3; n++)
    bvA[n] = *(const f16x8*)(lds + 8192 + ((wc * 3 + n) * 64 + aoff0) * 8);

#define GEMM_ITER(T, AVC, BVC, AVN, BVN)                                        \
  do {                                                                          \
    if ((T) + 3 < NT) STAGE((T) + 3);                                           \
    if ((T) + 1 < NT) {                                                         \
      const f16* nb_ = lds + (((T) + 1) & 3) * 14336;                           \
      _Pragma("unroll")                                                         \
      for (int m = 0; m < 8; m++)                                               \
        AVN[m] = *(const f16x8*)(nb_ + ((wr * 8 + m) * 64 + aoff0) * 8);        \
      _Pragma("unroll")                                                         \
      for (int n = 0; n < 3; n++)                                               \
        BVN[n] = *(const f16x8*)(nb_ + 8192 + ((wc * 3 + n) * 64 + aoff0) * 8); \
      WAIT_LGKM_11;                                                             \
    } else {                                                                    \
      WAIT_LGKM_0;                                                              \
    }                                                                           \
    __builtin_amdgcn_s_setprio(1);                                              \
    _Pragma("unroll")                                                           \
    for (int m = 0; m < 8; m++)                                                 \
      _Pragma("unroll")                                                         \
      for (int n = 0; n < 3; n++)                                               \
        acc[m][n] = __builtin_amdgcn_mfma_f32_16x16x32_f16(AVC[m], BVC[n],      \
                                                           acc[m][n], 0, 0, 0); \
    __builtin_amdgcn_s_setprio(0);                                              \
    if ((T) + 3 < NT)      { WAIT_VM_4; }                                       \
    else if ((T) + 2 < NT) { WAIT_VM_0; }                                       \
    RAW_BARRIER;                                                                \
  } while (0)

#pragma unroll 1
  for (int t = 0; t < NT; t += 2) {
    GEMM_ITER(t,     avA, bvA, avB, bvB);
    GEMM_ITER(t + 1, avB, bvB, avA, bvA);
  }
#undef GEMM_ITER

  float* nlds = (float*)lds;   // 96 x (stride 132) f32 tile; LDS dead after K-loop
#pragma unroll
  for (int m = 0; m < 8; m++) {
    const int row0 = brow + wr * 128 + m * 16 + kq * 4;
    const int bI = row0 >> 11, srow = row0 & 2047;
#pragma unroll
    for (int n = 0; n < 3; n++) {
      const int col = bcol + wc * 48 + n * 16 + fr;
      const float bb = bias[col];
      const float v0 = acc[m][n][0] + bb, v1 = acc[m][n][1] + bb;
      const float v2 = acc[m][n][2] + bb, v3 = acc[m][n][3] + bb;
      f16x4 w = {(f16)v0, (f16)v1, (f16)v2, (f16)v3};
      *(f16x4*)&CT[((long)bI * 3072 + col) * 2048 + srow] = w;
      const int tcol = bcol + wc * 48 + n * 16;
      if (tcol < 2048) {
        float h0 = v0 * v0 + v1 * v1;
        float h1 = v2 * v2 + v3 * v3;
        h0 += __shfl_xor(h0, 1, 64);
        h1 += __shfl_xor(h1, 1, 64);
        if (!(lane & 1)) {
          const int d2l = (wc * 48 + n * 16 + fr) >> 1;
          const int s2l = (wr * 128 + m * 16 + kq * 4) >> 1;
          nlds[d2l * 132 + s2l]     = h0;
          nlds[d2l * 132 + s2l + 1] = h1;
        }
      }
    }
  }
  if (bcol < 2048) {
    __syncthreads();
    const int bI = brow >> 11;
    const int s2b = (brow & 2047) >> 1;
    for (int i = tid; i < 96 * 64; i += 512) {
      const int r = i >> 6, c2 = i & 63;
      const int col = bcol + 2 * r;
      if (col < 2048) {
        const int tau = col >> 10;
        float* dst = (tau ? nkT : nqT)
                   + ((long)bI * 512 + ((col & 1023) >> 1)) * 1024 + s2b + c2 * 2;
        *(float2*)dst = *(float2*)&nlds[r * 132 + c2 * 2];
      }
    }
  }
}

// ============ 128x128 GEMM body: BK=64 hi-occupancy (32KB LDS), R16-verified ==============
template<typename OutT, bool TRANSC>
__device__ __forceinline__ void gemm_body_hi64(
    const f16* __restrict__ A, const f16* __restrict__ B, OutT* __restrict__ C,
    int K, int lda, int ldb, int ldc, float alpha,
    f16* lA, f16* lB, int brow, int bcol)
{
  const int tid = threadIdx.x;
  const int lane = tid & 63;
  const int wid = tid >> 6;
  const int wr = (wid >> 1) << 6;
  const int wc = (wid & 1) << 6;
  const int fr = lane & 15;
  const int kq = lane >> 4;

  const f16* gA = A + (long)brow * lda;
  const f16* gB = B + (long)bcol * ldb;
  int offA[4], offB[4], pd[4];
#pragma unroll
  for (int i = 0; i < 4; i++) {
    const int p = i * 256 + tid;
    const int r = p >> 3;
    const int c8 = (p & 7) ^ (r & 7);
    offA[i] = r * lda + c8 * 8;
    offB[i] = r * ldb + c8 * 8;
    pd[i] = p * 8;
  }

  f32x4 acc[4][4] = {};

  for (int t = 0; t < K; t += 64) {
#pragma unroll
    for (int i = 0; i < 4; i++) gload16(gA + offA[i] + t, lA + pd[i]);
#pragma unroll
    for (int i = 0; i < 4; i++) gload16(gB + offB[i] + t, lB + pd[i]);
    __syncthreads();
#pragma unroll
    for (int h = 0; h < 2; h++) {
      const int c8a = h * 4 + kq;
      f16x8 av[4], bv[4];
#pragma unroll
      for (int m = 0; m < 4; m++) {
        const int r = wr + m * 16 + fr;
        av[m] = *(const f16x8*)&lA[(r * 8 + (c8a ^ (r & 7))) * 8];
      }
#pragma unroll
      for (int n = 0; n < 4; n++) {
        const int r = wc + n * 16 + fr;
        bv[n] = *(const f16x8*)&lB[(r * 8 + (c8a ^ (r & 7))) * 8];
      }
#pragma unroll
      for (int m = 0; m < 4; m++)
#pragma unroll
        for (int n = 0; n < 4; n++)
          acc[m][n] = __builtin_amdgcn_mfma_f32_16x16x32_f16(av[m], bv[n], acc[m][n], 0, 0, 0);
    }
    __syncthreads();
  }

#pragma unroll
  for (int m = 0; m < 4; m++)
#pragma unroll
    for (int n = 0; n < 4; n++) {
      const int row0 = brow + wr + m * 16 + kq * 4;
      const int col  = bcol + wc + n * 16 + fr;
      if constexpr (TRANSC) {
        f16x4 v;
#pragma unroll
        for (int i = 0; i < 4; i++) v[i] = (f16)(acc[m][n][i] * alpha);
        *(f16x4*)&C[(long)col * ldc + row0] = v;
      } else {
#pragma unroll
        for (int i = 0; i < 4; i++)
          C[(long)(row0 + i) * ldc + col] = (OutT)(acc[m][n][i] * alpha);
      }
    }
}

// ============ 128x128 GEMM body: 4-buf deep pipeline (for 1-blk/CU grids), R16-verified ===
template<typename OutT, bool TRANSC>
__device__ __forceinline__ void gemm_body_pipe(
    const f16* __restrict__ A, const f16* __restrict__ B, OutT* __restrict__ C,
    int K, int lda, int ldb, int ldc, float alpha, f16* lds, int brow, int bcol)
{
  const int NT = K >> 5;
  const int tid = threadIdx.x;
  const int lane = tid & 63;
  const int wid = tid >> 6;
  const int wr = (wid >> 1) << 6;
  const int wc = (wid & 1) << 6;
  const int fr = lane & 15;
  const int kq = lane >> 4;
  const int kqsw = kq ^ ((fr >> 1) & 3);

  const int srow = tid >> 2;
  const int skq  = (tid & 3) ^ ((tid >> 3) & 3);
  const f16* gA0 = A + (long)(brow + srow) * lda + skq * 8;
  const f16* gA1 = A + (long)(brow + 64 + srow) * lda + skq * 8;
  const f16* gB0 = B + (long)(bcol + srow) * ldb + skq * 8;
  const f16* gB1 = B + (long)(bcol + 64 + srow) * ldb + skq * 8;
  const int dA0 = tid * 8, dA1 = 2048 + tid * 8;
  const int dB0 = 4096 + tid * 8, dB1 = 6144 + tid * 8;

  auto STAGE = [&](int t) {
    f16* base = lds + (t & 3) * 8192;
    const int off = t * 32;
    gload16(gA0 + off, base + dA0);
    gload16(gA1 + off, base + dA1);
    gload16(gB0 + off, base + dB0);
    gload16(gB1 + off, base + dB1);
  };

  f32x4 acc[4][4] = {};

  STAGE(0); STAGE(1); STAGE(2);
  WAIT_VM_8;
  RAW_BARRIER;

#pragma unroll 1
  for (int t = 0; t < NT; ++t) {
    if (t + 3 < NT) STAGE(t + 3);
    SCHED_FENCE;
    const f16* base = lds + (t & 3) * 8192;
    f16x8 av[4], bv[4];
#pragma unroll
    for (int m = 0; m < 4; m++)
      av[m] = *(const f16x8*)(base + (wr + m * 16 + fr) * 32 + kqsw * 8);
#pragma unroll
    for (int n = 0; n < 4; n++)
      bv[n] = *(const f16x8*)(base + 4096 + (wc + n * 16 + fr) * 32 + kqsw * 8);
    __builtin_amdgcn_s_setprio(1);
#pragma unroll
    for (int m = 0; m < 4; m++)
#pragma unroll
      for (int n = 0; n < 4; n++)
        acc[m][n] = __builtin_amdgcn_mfma_f32_16x16x32_f16(av[m], bv[n], acc[m][n], 0, 0, 0);
    __builtin_amdgcn_s_setprio(0);
    if (t + 1 < NT) {
      WAIT_LGKM_0;
      if (t + 3 < NT)      { WAIT_VM_8; }
      else if (t + 2 < NT) { WAIT_VM_4; }
      else                 { WAIT_VM_0; }
      RAW_BARRIER;
    }
  }

#pragma unroll
  for (int m = 0; m < 4; m++)
#pragma unroll
    for (int n = 0; n < 4; n++) {
      const int row0 = brow + wr + m * 16 + kq * 4;
      const int col  = bcol + wc + n * 16 + fr;
      if constexpr (TRANSC) {
        f16x4 v;
#pragma unroll
        for (int i = 0; i < 4; i++) v[i] = (f16)(acc[m][n][i] * alpha);
        *(f16x4*)&C[(long)col * ldc + row0] = v;
      } else {
#pragma unroll
        for (int i = 0; i < 4; i++)
          C[(long)(row0 + i) * ldc + col] = (OutT)(acc[m][n][i] * alpha);
      }
    }
}

// L1 (512 hi64, XCD swz): z<4 -> B2n_b = x^T.v /32 ; else Zt_b = x^T.WO_ /32
__global__ __launch_bounds__(256)
void gemmL1(const f16* __restrict__ xT, const f16* __restrict__ qkvT,
            const f16* __restrict__ WOT, f16* __restrict__ B2n, f16* __restrict__ Zt)
{
  __shared__ f16 lA[8192];
  __shared__ f16 lB[8192];
  const int s = blockIdx.x;
  const int tile = (s & 7) * 64 + (s >> 3);
  const int z = tile >> 6, rem = tile & 63;
  const int brow = (rem >> 3) << 7, bcol = (rem & 7) << 7;
  const int b = z & 3;
  const f16* A = xT + (long)b * 1024 * 2048;
  const f16* B; f16* C;
  if (z < 4) { B = qkvT + (long)b * 3072 * 2048 + 2048L * 2048; C = B2n + (long)b * 1024 * 1024; }
  else       { B = WOT + (long)b * 1024 * 2048;                 C = Zt  + (long)b * 1024 * 1024; }
  gemm_body_hi64<f16, false>(A, B, C, 2048, 2048, 2048, 1024, 0.03125f, lA, lB, brow, bcol);
}

// L2 (512 hi64, XCD swz): z<4 -> A1_b = Pq^T.Pk /32 (direct from masked qkvT); else PT_b
__global__ __launch_bounds__(256)
void gemmL2(const f16* __restrict__ qkvT, f16* __restrict__ A1,
            const f16* __restrict__ B2n, const f16* __restrict__ Zt, f16* __restrict__ PT)
{
  __shared__ f16 lA[8192];
  __shared__ f16 lB[8192];
  const int s = blockIdx.x;
  const int tile = (s & 7) * 64 + (s >> 3);
  const int z = tile >> 6, rem = tile & 63;
  const int brow = (rem >> 3) << 7, bcol = (rem & 7) << 7;
  const int b = z & 3;
  if (z < 4) {
    const f16* q = qkvT + (long)b * 3072 * 2048;
    const f16* k = qkvT + (long)b * 3072 * 2048 + 1024L * 2048;
    gemm_body_hi64<f16, false>(q, k, A1 + (long)b * 1024 * 1024,
                               2048, 2048, 2048, 1024, 0.03125f, lA, lB, brow, bcol);
  } else {
    gemm_body_hi64<f16, true>(B2n + (long)b * 1024 * 1024, Zt + (long)b * 1024 * 1024,
                              PT + (long)b * 1024 * 1024,
                              1024, 1024, 1024, 1024, 0.25f, lA, lB, brow, bcol);
  }
}

// L3 (256 pipe, XCD swz): M2T_b = (A1.P)^T
__global__ __launch_bounds__(256)
void gemmL3(const f16* __restrict__ A1, const f16* __restrict__ PT, f16* __restrict__ M2T)
{
  __shared__ f16 lds[32768];
  const int s = blockIdx.x;
  const int tile = (s & 7) * 32 + (s >> 3);
  const int b = tile >> 6, rem = tile & 63;
  gemm_body_pipe<f16, true>(A1 + (long)b * 1024 * 1024, PT + (long)b * 1024 * 1024,
                            M2T + (long)b * 1024 * 1024,
                            1024, 1024, 1024, 1024, 1.f, lds,
                            (rem >> 3) << 7, (rem & 7) << 7);
}

// L4 (512 hi64, XCD swz): out_b = x.M2 * 4096
__global__ __launch_bounds__(256)
void gemmL4(const f16* __restrict__ xh, const f16* __restrict__ M2T, float* __restrict__ out)
{
  __shared__ f16 lA[8192];
  __shared__ f16 lB[8192];
  const int s = blockIdx.x;
  const int tile = (s & 7) * 64 + (s >> 3);
  const int b = tile >> 7, rem = tile & 127;
  gemm_body_hi64<float, false>(xh + (long)b * 2048 * 1024, M2T + (long)b * 1024 * 1024,
                               out + (long)b * 2048 * 1024,
                               1024, 1024, 1024, 1024, 4096.f, lA, lB,
                               (rem >> 3) << 7, (rem & 7) << 7);
}

// ---------------- cvt combo: z<8192 x->(xh,xT); z<11264 Wqkv->wh;
//                  z<13312 WO row-norms + WO->woh f16; else select_init
__global__ __launch_bounds__(256)
void cvt_combo(const float* __restrict__ x, f16* __restrict__ xh, f16* __restrict__ xT,
               const float* __restrict__ Wqkv, f16* __restrict__ wh,
               const float* __restrict__ WO, float* __restrict__ wno, f16* __restrict__ woh,
               unsigned* __restrict__ hist, unsigned* __restrict__ prefix,
               unsigned* __restrict__ rankrem) {
  const int z = blockIdx.x;
  const int tid = threadIdx.x;
  if (z < 8192) {
    __shared__ f16 t[32][33];
    const int b = z >> 11, r = z & 2047;
    const int s0 = (r & 63) * 32, d0 = (r >> 6) * 32;
    const int tx = tid & 31, ty = tid >> 5;
#pragma unroll
    for (int j = 0; j < 32; j += 8) {
      const long idx = ((long)b * 2048 + s0 + ty + j) * 1024 + d0 + tx;
      f16 h = (f16)x[idx];
      xh[idx] = h;
      t[ty + j][tx] = h;
    }
    __syncthreads();
#pragma unroll
    for (int j = 0; j < 32; j += 8)
      xT[((long)b * 1024 + d0 + ty + j) * 2048 + s0 + tx] = t[tx][ty + j];
  } else if (z < 11264) {
    const long i = (long)(z - 8192) * 256 + tid;
    float4 v = ((const float4*)Wqkv)[i];
    f16x4 o = {(f16)v.x, (f16)v.y, (f16)v.z, (f16)v.w};
    ((f16x4*)wh)[i] = o;
  } else if (z < 13312) {
    const int wid = tid >> 6, lane = tid & 63;
    const long row = (long)(z - 11264) * 4 + wid;
    const float* p = WO + row * 1024;
    float s = 0.f;
#pragma unroll
    for (int j = 0; j < 4; j++) {
      float4 v = *(const float4*)(p + lane * 4 + j * 256);
      s += v.x*v.x + v.y*v.y + v.z*v.z + v.w*v.w;
      f16x4 o = {(f16)v.x, (f16)v.y, (f16)v.z, (f16)v.w};
      *(f16x4*)(woh + row * 1024 + lane * 4 + j * 256) = o;
    }
    for (int off = 32; off; off >>= 1) s += __shfl_down(s, off, 64);
    if (lane == 0) wno[row] = s;
  } else {
    const int i = (z - 13312) * 256 + tid;
    if (i < 12 * 4096) hist[i] = 0;
    if (i < 12) { prefix[i] = 0; rankrem[i] = (i < 8) ? 262144u : 1024u; }
  }
}

// ---------------- radix-select: 2 passes x 4096 bins (bits 31:20, 19:8)
__global__ __launch_bounds__(256)
void hist_pass(const float* __restrict__ nqT, const float* __restrict__ nkT,
               const float* __restrict__ wno, unsigned* __restrict__ hist,
               const unsigned* __restrict__ prefix,
               int shift, int nbins, unsigned himask) {
  __shared__ unsigned lh[4096];
  const int pid = blockIdx.y;
  for (int i = threadIdx.x; i < nbins; i += 256) lh[i] = 0;
  __syncthreads();
  const float* base; long N;
  if (pid < 4)      { base = nqT + (long)pid       * 524288; N = 524288; }
  else if (pid < 8) { base = nkT + (long)(pid - 4) * 524288; N = 524288; }
  else              { base = wno + (long)(pid - 8) * 2048;   N = 2048;  }
  const unsigned pref = prefix[pid];
  long chunk = (N + gridDim.x - 1) / gridDim.x;
  long s = (long)blockIdx.x * chunk;
  long e = s + chunk; if (e > N) e = N;
  for (long i = s + threadIdx.x; i < e; i += 256) {
    unsigned u = __float_as_uint(base[i]);
    if ((u & himask) == pref) atomicAdd(&lh[(u >> shift) & (nbins - 1)], 1u);
  }
  __syncthreads();
  for (int i = threadIdx.x; i < nbins; i += 256)
    if (lh[i]) atomicAdd(&hist[pid * 4096 + i], lh[i]);
}

__global__ __launch_bounds__(256)
void scan_pass(unsigned* __restrict__ hist, unsigned* __restrict__ prefix,
               unsigned* __restrict__ rankrem, float* __restrict__ thr,
               int shift, int nbins, int final_pass) {
  __shared__ unsigned buf[2][256];
  const int pid = blockIdx.x;
  const int tid = threadIdx.x;
  unsigned* h = hist + pid * 4096;
  const int per = nbins >> 8;
  const unsigned r = rankrem[pid];
  const unsigned oldpref = prefix[pid];
  unsigned local[16];
  unsigned s = 0;
#pragma unroll
  for (int j = 0; j < 16; j++) {
    if (j < per) {
      local[j] = h[tid * per + j];
      h[tid * per + j] = 0;
      s += local[j];
    }
  }
  buf[0][tid] = s;
  __syncthreads();
  int src = 0;
#pragma unroll
  for (int d = 1; d < 256; d <<= 1) {
    unsigned v = buf[src][tid];
    if (tid >= d) v += buf[src][tid - d];
    buf[src ^ 1][tid] = v;
    __syncthreads();
    src ^= 1;
  }
  const unsigned incl = buf[src][tid];
  const unsigned excl = incl - s;
  if (excl <= r && r < incl) {
    unsigned accu = excl;
#pragma unroll
    for (int j = 0; j < 16; j++) {
      if (j < per) {
        if (accu + local[j] > r) {
          rankrem[pid] = r - accu;
          unsigned np = oldpref | ((unsigned)(tid * per + j) << shift);
          prefix[pid] = np;
          if (final_pass) thr[pid] = __uint_as_float(np);
          break;
        }
        accu += local[j];
      }
    }
  }
}

// ---------------- mask combo: z<8192 in-place q/k zeroing; else WOT from woh (f16)
__global__ __launch_bounds__(256)
void mask_combo(f16* __restrict__ qkvT, const float* __restrict__ nqT,
                const float* __restrict__ nkT, const float* __restrict__ thr,
                const f16* __restrict__ woh, const float* __restrict__ wno,
                f16* __restrict__ WOT) {
  const int z = blockIdx.x;
  const int tid = threadIdx.x;
  if (z < 8192) {
    const int d  = z & 1023;
    const int tau = (z >> 10) & 1;
    const int bI = z >> 11;
    const float t = thr[tau * 4 + bI];
    const float4 nv = *(const float4*)((tau ? nkT : nqT)
                       + ((long)bI * 512 + (d >> 1)) * 1024 + tid * 4);
    unsigned* pb = (unsigned*)(qkvT + ((long)bI * 3072 + tau * 1024 + d) * 2048 + tid * 8);
    if (nv.x < t) pb[0] = 0u;
    if (nv.y < t) pb[1] = 0u;
    if (nv.z < t) pb[2] = 0u;
    if (nv.w < t) pb[3] = 0u;
  } else {
    __shared__ f16 t[32][33];
    const int zz = z - 8192;
    const int b = zz >> 11, r = zz & 2047;
    const int s0 = (r & 63) * 32, d0 = (r >> 6) * 32;
    const int tx = tid & 31, ty = tid >> 5;
    const float tb = thr[8 + b];
#pragma unroll
    for (int j = 0; j < 32; j += 8) {
      const int s = s0 + ty + j;
      const bool keep = wno[(long)b * 2048 + s] >= tb;
      t[ty + j][tx] = keep ? woh[((long)b * 2048 + s) * 1024 + d0 + tx] : (f16)0.f;
    }
    __syncthreads();
#pragma unroll
    for (int j = 0; j < 32; j += 8)
      WOT[((long)b * 1024 + d0 + ty + j) * 2048 + s0 + tx] = t[tx][ty + j];
  }
}

extern "C" void kernel_launch(void* const* d_in, const int* in_sizes, int n_in,
                              void* d_out, int out_size, void* d_ws, size_t ws_size,
                              hipStream_t stream) {
  const float* x    = (const float*)d_in[0];
  const float* Wqkv = (const float*)d_in[1];
  const float* bqkv = (const float*)d_in[2];
  const float* WO   = (const float*)d_in[3];
  float* out = (float*)d_out;

  char* w = (char*)d_ws;
  auto alloc = [&](size_t bytes) { char* p = w; w += (bytes + 255) & ~(size_t)255; return p; };
  f16*      xh      = (f16*)alloc(8192L * 1024 * 2);
  f16*      wh      = (f16*)alloc(3072L * 1024 * 2);
  f16*      xT      = (f16*)alloc(4L * 1024 * 2048 * 2);
  f16*      qkvT    = (f16*)alloc(4L * 3072 * 2048 * 2);
  float*    nqT     = (float*)alloc(4L * 524288 * 4);
  float*    nkT     = (float*)alloc(4L * 524288 * 4);
  float*    wno     = (float*)alloc(8192L * 4);
  f16*      woh     = (f16*)alloc(8192L * 1024 * 2);
  unsigned* hist    = (unsigned*)alloc(12L * 4096 * 4);
  unsigned* prefix  = (unsigned*)alloc(256);
  unsigned* rankrem = (unsigned*)alloc(256);
  float*    thr     = (float*)alloc(256);
  f16*      WOT     = (f16*)alloc(4L * 1024 * 2048 * 2);
  f16*      B2n     = (f16*)alloc(4L * 1024 * 1024 * 2);
  f16*      Zt      = (f16*)alloc(4L * 1024 * 1024 * 2);
  f16*      A1      = (f16*)alloc(4L * 1024 * 1024 * 2);
  f16*      PT      = (f16*)alloc(4L * 1024 * 1024 * 2);
  f16*      M2T     = (f16*)alloc(4L * 1024 * 1024 * 2);
  if ((size_t)(w - (char*)d_ws) > ws_size) return;

  // 1. conversions + WO norms/f16 + select-init
  cvt_combo<<<13504, 256, 0, stream>>>(x, xh, xT, Wqkv, wh, WO, wno, woh,
                                       hist, prefix, rankrem);
  // 2. qkv GEMM (frozen body) -> qkvT + LDS-staged d-major tile-norms (padded)
  gemm256_qkv<<<512, 512, 0, stream>>>(xh, wh, qkvT, bqkv, nqT, nkT);
  // 3. medians via 2-pass radix select (4 launches: simple, measured-fast)
  hist_pass<<<dim3(32, 12), 256, 0, stream>>>(nqT, nkT, wno, hist, prefix, 20, 4096, 0u);
  scan_pass<<<12, 256, 0, stream>>>(hist, prefix, rankrem, thr, 20, 4096, 0);
  hist_pass<<<dim3(32, 12), 256, 0, stream>>>(nqT, nkT, wno, hist, prefix, 8, 4096, 0xFFF00000u);
  scan_pass<<<12, 256, 0, stream>>>(hist, prefix, rankrem, thr, 8, 4096, 1);
  // 4. masks: in-place q/k zeroing + WOT from f16 woh
  mask_combo<<<16384, 256, 0, stream>>>(qkvT, nqT, nkT, thr, woh, wno, WOT);
  // 5. chain (R18-best assignment, fully XCD-swizzled)
  gemmL1<<<512, 256, 0, stream>>>(xT, qkvT, WOT, B2n, Zt);
  gemmL2<<<512, 256, 0, stream>>>(qkvT, A1, B2n, Zt, PT);
  gemmL3<<<256, 256, 0, stream>>>(A1, PT, M2T);
  gemmL4<<<512, 256, 0, stream>>>(xh, M2T, out);
}

// Round 21
// 314.978 us; speedup vs baseline: 1.1790x; 1.0017x over previous
//
#include <hip/hip_runtime.h>

typedef _Float16 f16;
typedef _Float16 f16x8 __attribute__((ext_vector_type(8)));
typedef _Float16 f16x4 __attribute__((ext_vector_type(4)));
typedef float f32x4 __attribute__((ext_vector_type(4)));

__device__ __forceinline__ void gload16(const void* g, void* l) {
  __builtin_amdgcn_global_load_lds(
      (const __attribute__((address_space(1))) void*)g,
      (__attribute__((address_space(3))) void*)l, 16, 0, 0);
}

#define SCHED_FENCE __builtin_amdgcn_sched_barrier(0)
#define RAW_BARRIER do { SCHED_FENCE; __builtin_amdgcn_s_barrier(); SCHED_FENCE; } while (0)
#define WAIT_VM_0    do { asm volatile("s_waitcnt vmcnt(0)"     ::: "memory"); SCHED_FENCE; } while (0)
#define WAIT_VM_4    do { asm volatile("s_waitcnt vmcnt(4)"     ::: "memory"); SCHED_FENCE; } while (0)
#define WAIT_VM_8    do { asm volatile("s_waitcnt vmcnt(8)"     ::: "memory"); SCHED_FENCE; } while (0)
#define WAIT_LGKM_0  do { asm volatile("s_waitcnt lgkmcnt(0)"   ::: "memory"); SCHED_FENCE; } while (0)
#define WAIT_LGKM_11 do { asm volatile("s_waitcnt lgkmcnt(11)"  ::: "memory"); SCHED_FENCE; } while (0)

// ============ qkv GEMM: frozen R7 body; LDS-staged d-major norms (stride-132 padded) ======
__global__ __launch_bounds__(512, 2)
void gemm256_qkv(const f16* __restrict__ A, const f16* __restrict__ B,
                 f16* __restrict__ CT, const float* __restrict__ bias,
                 float* __restrict__ nqT, float* __restrict__ nkT)
{
  __shared__ f16 lds[4 * 14336];
  const int s = blockIdx.x;
  const int tile = (s & 7) * 64 + (s >> 3);
  const int brow = (tile >> 4) << 8;
  const int bcol = (tile & 15) * 192;
  const int NT = 32;
  const int tid = threadIdx.x;
  const int lane = tid & 63;
  const int wid = tid >> 6;
  const int wr = wid >> 2;
  const int wc = wid & 3;
  const int fr = lane & 15;
  const int kq = lane >> 4;

  const f16* pA[2]; const f16* pB[2]; int pdA[2], pdB[2];
#pragma unroll
  for (int i = 0; i < 2; i++) {
    const int p = wid * 128 + i * 64 + lane;
    const int rr = ((p >> 6) << 4) | ((p >> 2) & 15);
    const int c4 = (p & 3) ^ ((p >> 3) & 3);
    pA[i] = A + (long)(brow + rr) * 1024 + c4 * 8;
    pdA[i] = p * 8;
    const int g = (p >= 768) ? p - 256 : p;
    const int rb = ((g >> 6) << 4) | ((g >> 2) & 15);
    const int cb = (g & 3) ^ ((g >> 3) & 3);
    pB[i] = B + (long)(bcol + rb) * 1024 + cb * 8;
    pdB[i] = 8192 + g * 8;
  }

  auto STAGE = [&](int t) {
    f16* base = lds + (t & 3) * 14336;
    const int off = t * 32;
#pragma unroll
    for (int i = 0; i < 2; i++) {
      gload16(pA[i] + off, base + pdA[i]);
      gload16(pB[i] + off, base + pdB[i]);
    }
  };

  const int aoff0 = fr * 4 + (kq ^ ((fr >> 1) & 3));
  f32x4 acc[8][3] = {};
  f16x8 avA[8], bvA[3], avB[8], bvB[3];

  STAGE(0); STAGE(1); STAGE(2);
  WAIT_VM_4;
  RAW_BARRIER;
#pragma unroll
  for (int m = 0; m < 8; m++)
    avA[m] = *(const f16x8*)(lds + ((wr * 8 + m) * 64 + aoff0) * 8);
#pragma unroll
  for (int n = 0; n < 3; n++)
    bvA[n] = *(const f16x8*)(lds + 8192 + ((wc * 3 + n) * 64 + aoff0) * 8);

#define GEMM_ITER(T, AVC, BVC, AVN, BVN)                                        \
  do {                                                                          \
    if ((T) + 3 < NT) STAGE((T) + 3);                                           \
    if ((T) + 1 < NT) {                                                         \
      const f16* nb_ = lds + (((T) + 1) & 3) * 14336;                           \
      _Pragma("unroll")                                                         \
      for (int m = 0; m < 8; m++)                                               \
        AVN[m] = *(const f16x8*)(nb_ + ((wr * 8 + m) * 64 + aoff0) * 8);        \
      _Pragma("unroll")                                                         \
      for (int n = 0; n < 3; n++)                                               \
        BVN[n] = *(const f16x8*)(nb_ + 8192 + ((wc * 3 + n) * 64 + aoff0) * 8); \
      WAIT_LGKM_11;                                                             \
    } else {                                                                    \
      WAIT_LGKM_0;                                                              \
    }                                                                           \
    __builtin_amdgcn_s_setprio(1);                                              \
    _Pragma("unroll")                                                           \
    for (int m = 0; m < 8; m++)                                                 \
      _Pragma("unroll")                                                         \
      for (int n = 0; n < 3; n++)                                               \
        acc[m][n] = __builtin_amdgcn_mfma_f32_16x16x32_f16(AVC[m], BVC[n],      \
                                                           acc[m][n], 0, 0, 0); \
    __builtin_amdgcn_s_setprio(0);                                              \
    if ((T) + 3 < NT)      { WAIT_VM_4; }                                       \
    else if ((T) + 2 < NT) { WAIT_VM_0; }                                       \
    RAW_BARRIER;                                                                \
  } while (0)

#pragma unroll 1
  for (int t = 0; t < NT; t += 2) {
    GEMM_ITER(t,     avA, bvA, avB, bvB);
    GEMM_ITER(t + 1, avB, bvB, avA, bvA);
  }
#undef GEMM_ITER

  float* nlds = (float*)lds;   // 96 x (stride 132) f32 tile; LDS dead after K-loop
#pragma unroll
  for (int m = 0; m < 8; m++) {
    const int row0 = brow + wr * 128 + m * 16 + kq * 4;
    const int bI = row0 >> 11, srow = row0 & 2047;
#pragma unroll
    for (int n = 0; n < 3; n++) {
      const int col = bcol + wc * 48 + n * 16 + fr;
      const float bb = bias[col];
      const float v0 = acc[m][n][0] + bb, v1 = acc[m][n][1] + bb;
      const float v2 = acc[m][n][2] + bb, v3 = acc[m][n][3] + bb;
      f16x4 w = {(f16)v0, (f16)v1, (f16)v2, (f16)v3};
      *(f16x4*)&CT[((long)bI * 3072 + col) * 2048 + srow] = w;
      const int tcol = bcol + wc * 48 + n * 16;
      if (tcol < 2048) {
        float h0 = v0 * v0 + v1 * v1;
        float h1 = v2 * v2 + v3 * v3;
        h0 += __shfl_xor(h0, 1, 64);
        h1 += __shfl_xor(h1, 1, 64);
        if (!(lane & 1)) {
          const int d2l = (wc * 48 + n * 16 + fr) >> 1;
          const int s2l = (wr * 128 + m * 16 + kq * 4) >> 1;
          nlds[d2l * 132 + s2l]     = h0;
          nlds[d2l * 132 + s2l + 1] = h1;
        }
      }
    }
  }
  if (bcol < 2048) {
    __syncthreads();
    const int bI = brow >> 11;
    const int s2b = (brow & 2047) >> 1;
    for (int i = tid; i < 96 * 64; i += 512) {
      const int r = i >> 6, c2 = i & 63;
      const int col = bcol + 2 * r;
      if (col < 2048) {
        const int tau = col >> 10;
        float* dst = (tau ? nkT : nqT)
                   + ((long)bI * 512 + ((col & 1023) >> 1)) * 1024 + s2b + c2 * 2;
        *(float2*)dst = *(float2*)&nlds[r * 132 + c2 * 2];
      }
    }
  }
}

// ============ 128x128 GEMM body: BK=64 hi-occupancy (32KB LDS), R16-verified ==============
template<typename OutT, bool TRANSC>
__device__ __forceinline__ void gemm_body_hi64(
    const f16* __restrict__ A, const f16* __restrict__ B, OutT* __restrict__ C,
    int K, int lda, int ldb, int ldc, float alpha,
    f16* lA, f16* lB, int brow, int bcol)
{
  const int tid = threadIdx.x;
  const int lane = tid & 63;
  const int wid = tid >> 6;
  const int wr = (wid >> 1) << 6;
  const int wc = (wid & 1) << 6;
  const int fr = lane & 15;
  const int kq = lane >> 4;

  const f16* gA = A + (long)brow * lda;
  const f16* gB = B + (long)bcol * ldb;
  int offA[4], offB[4], pd[4];
#pragma unroll
  for (int i = 0; i < 4; i++) {
    const int p = i * 256 + tid;
    const int r = p >> 3;
    const int c8 = (p & 7) ^ (r & 7);
    offA[i] = r * lda + c8 * 8;
    offB[i] = r * ldb + c8 * 8;
    pd[i] = p * 8;
  }

  f32x4 acc[4][4] = {};

  for (int t = 0; t < K; t += 64) {
#pragma unroll
    for (int i = 0; i < 4; i++) gload16(gA + offA[i] + t, lA + pd[i]);
#pragma unroll
    for (int i = 0; i < 4; i++) gload16(gB + offB[i] + t, lB + pd[i]);
    __syncthreads();
#pragma unroll
    for (int h = 0; h < 2; h++) {
      const int c8a = h * 4 + kq;
      f16x8 av[4], bv[4];
#pragma unroll
      for (int m = 0; m < 4; m++) {
        const int r = wr + m * 16 + fr;
        av[m] = *(const f16x8*)&lA[(r * 8 + (c8a ^ (r & 7))) * 8];
      }
#pragma unroll
      for (int n = 0; n < 4; n++) {
        const int r = wc + n * 16 + fr;
        bv[n] = *(const f16x8*)&lB[(r * 8 + (c8a ^ (r & 7))) * 8];
      }
#pragma unroll
      for (int m = 0; m < 4; m++)
#pragma unroll
        for (int n = 0; n < 4; n++)
          acc[m][n] = __builtin_amdgcn_mfma_f32_16x16x32_f16(av[m], bv[n], acc[m][n], 0, 0, 0);
    }
    __syncthreads();
  }

#pragma unroll
  for (int m = 0; m < 4; m++)
#pragma unroll
    for (int n = 0; n < 4; n++) {
      const int row0 = brow + wr + m * 16 + kq * 4;
      const int col  = bcol + wc + n * 16 + fr;
      if constexpr (TRANSC) {
        f16x4 v;
#pragma unroll
        for (int i = 0; i < 4; i++) v[i] = (f16)(acc[m][n][i] * alpha);
        *(f16x4*)&C[(long)col * ldc + row0] = v;
      } else {
#pragma unroll
        for (int i = 0; i < 4; i++)
          C[(long)(row0 + i) * ldc + col] = (OutT)(acc[m][n][i] * alpha);
      }
    }
}

// ============ 128x128 GEMM body: 4-buf deep pipeline (for 1-blk/CU grids), R16-verified ===
template<typename OutT, bool TRANSC>
__device__ __forceinline__ void gemm_body_pipe(
    const f16* __restrict__ A, const f16* __restrict__ B, OutT* __restrict__ C,
    int K, int lda, int ldb, int ldc, float alpha, f16* lds, int brow, int bcol)
{
  const int NT = K >> 5;
  const int tid = threadIdx.x;
  const int lane = tid & 63;
  const int wid = tid >> 6;
  const int wr = (wid >> 1) << 6;
  const int wc = (wid & 1) << 6;
  const int fr = lane & 15;
  const int kq = lane >> 4;
  const int kqsw = kq ^ ((fr >> 1) & 3);

  const int srow = tid >> 2;
  const int skq  = (tid & 3) ^ ((tid >> 3) & 3);
  const f16* gA0 = A + (long)(brow + srow) * lda + skq * 8;
  const f16* gA1 = A + (long)(brow + 64 + srow) * lda + skq * 8;
  const f16* gB0 = B + (long)(bcol + srow) * ldb + skq * 8;
  const f16* gB1 = B + (long)(bcol + 64 + srow) * ldb + skq * 8;
  const int dA0 = tid * 8, dA1 = 2048 + tid * 8;
  const int dB0 = 4096 + tid * 8, dB1 = 6144 + tid * 8;

  auto STAGE = [&](int t) {
    f16* base = lds + (t & 3) * 8192;
    const int off = t * 32;
    gload16(gA0 + off, base + dA0);
    gload16(gA1 + off, base + dA1);
    gload16(gB0 + off, base + dB0);
    gload16(gB1 + off, base + dB1);
  };

  f32x4 acc[4][4] = {};

  STAGE(0); STAGE(1); STAGE(2);
  WAIT_VM_8;
  RAW_BARRIER;

#pragma unroll 1
  for (int t = 0; t < NT; ++t) {
    if (t + 3 < NT) STAGE(t + 3);
    SCHED_FENCE;
    const f16* base = lds + (t & 3) * 8192;
    f16x8 av[4], bv[4];
#pragma unroll
    for (int m = 0; m < 4; m++)
      av[m] = *(const f16x8*)(base + (wr + m * 16 + fr) * 32 + kqsw * 8);
#pragma unroll
    for (int n = 0; n < 4; n++)
      bv[n] = *(const f16x8*)(base + 4096 + (wc + n * 16 + fr) * 32 + kqsw * 8);
    __builtin_amdgcn_s_setprio(1);
#pragma unroll
    for (int m = 0; m < 4; m++)
#pragma unroll
      for (int n = 0; n < 4; n++)
        acc[m][n] = __builtin_amdgcn_mfma_f32_16x16x32_f16(av[m], bv[n], acc[m][n], 0, 0, 0);
    __builtin_amdgcn_s_setprio(0);
    if (t + 1 < NT) {
      WAIT_LGKM_0;
      if (t + 3 < NT)      { WAIT_VM_8; }
      else if (t + 2 < NT) { WAIT_VM_4; }
      else                 { WAIT_VM_0; }
      RAW_BARRIER;
    }
  }

#pragma unroll
  for (int m = 0; m < 4; m++)
#pragma unroll
    for (int n = 0; n < 4; n++) {
      const int row0 = brow + wr + m * 16 + kq * 4;
      const int col  = bcol + wc + n * 16 + fr;
      if constexpr (TRANSC) {
        f16x4 v;
#pragma unroll
        for (int i = 0; i < 4; i++) v[i] = (f16)(acc[m][n][i] * alpha);
        *(f16x4*)&C[(long)col * ldc + row0] = v;
      } else {
#pragma unroll
        for (int i = 0; i < 4; i++)
          C[(long)(row0 + i) * ldc + col] = (OutT)(acc[m][n][i] * alpha);
      }
    }
}

// L1 (512 hi64, XCD swz): z<4 -> B2n_b = x^T.v /32 ; else Zt_b = x^T.WO_ /32
__global__ __launch_bounds__(256)
void gemmL1(const f16* __restrict__ xT, const f16* __restrict__ qkvT,
            const f16* __restrict__ WOT, f16* __restrict__ B2n, f16* __restrict__ Zt)
{
  __shared__ f16 lA[8192];
  __shared__ f16 lB[8192];
  const int s = blockIdx.x;
  const int tile = (s & 7) * 64 + (s >> 3);
  const int z = tile >> 6, rem = tile & 63;
  const int brow = (rem >> 3) << 7, bcol = (rem & 7) << 7;
  const int b = z & 3;
  const f16* A = xT + (long)b * 1024 * 2048;
  const f16* B; f16* C;
  if (z < 4) { B = qkvT + (long)b * 3072 * 2048 + 2048L * 2048; C = B2n + (long)b * 1024 * 1024; }
  else       { B = WOT + (long)b * 1024 * 2048;                 C = Zt  + (long)b * 1024 * 1024; }
  gemm_body_hi64<f16, false>(A, B, C, 2048, 2048, 2048, 1024, 0.03125f, lA, lB, brow, bcol);
}

// L2 (512 hi64, XCD swz): z<4 -> A1_b = Pq^T.Pk /32 (direct from masked qkvT); else PT_b
__global__ __launch_bounds__(256)
void gemmL2(const f16* __restrict__ qkvT, f16* __restrict__ A1,
            const f16* __restrict__ B2n, const f16* __restrict__ Zt, f16* __restrict__ PT)
{
  __shared__ f16 lA[8192];
  __shared__ f16 lB[8192];
  const int s = blockIdx.x;
  const int tile = (s & 7) * 64 + (s >> 3);
  const int z = tile >> 6, rem = tile & 63;
  const int brow = (rem >> 3) << 7, bcol = (rem & 7) << 7;
  const int b = z & 3;
  if (z < 4) {
    const f16* q = qkvT + (long)b * 3072 * 2048;
    const f16* k = qkvT + (long)b * 3072 * 2048 + 1024L * 2048;
    gemm_body_hi64<f16, false>(q, k, A1 + (long)b * 1024 * 1024,
                               2048, 2048, 2048, 1024, 0.03125f, lA, lB, brow, bcol);
  } else {
    gemm_body_hi64<f16, true>(B2n + (long)b * 1024 * 1024, Zt + (long)b * 1024 * 1024,
                              PT + (long)b * 1024 * 1024,
                              1024, 1024, 1024, 1024, 0.25f, lA, lB, brow, bcol);
  }
}

// L3 (256 pipe, XCD swz): M2T_b = (A1.P)^T
__global__ __launch_bounds__(256)
void gemmL3(const f16* __restrict__ A1, const f16* __restrict__ PT, f16* __restrict__ M2T)
{
  __shared__ f16 lds[32768];
  const int s = blockIdx.x;
  const int tile = (s & 7) * 32 + (s >> 3);
  const int b = tile >> 6, rem = tile & 63;
  gemm_body_pipe<f16, true>(A1 + (long)b * 1024 * 1024, PT + (long)b * 1024 * 1024,
                            M2T + (long)b * 1024 * 1024,
                            1024, 1024, 1024, 1024, 1.f, lds,
                            (rem >> 3) << 7, (rem & 7) << 7);
}

// L4 (512 hi64, XCD swz): out_b = x.M2 * 4096
__global__ __launch_bounds__(256)
void gemmL4(const f16* __restrict__ xh, const f16* __restrict__ M2T, float* __restrict__ out)
{
  __shared__ f16 lA[8192];
  __shared__ f16 lB[8192];
  const int s = blockIdx.x;
  const int tile = (s & 7) * 64 + (s >> 3);
  const int b = tile >> 7, rem = tile & 127;
  gemm_body_hi64<float, false>(xh + (long)b * 2048 * 1024, M2T + (long)b * 1024 * 1024,
                               out + (long)b * 2048 * 1024,
                               1024, 1024, 1024, 1024, 4096.f, lA, lB,
                               (rem >> 3) << 7, (rem & 7) << 7);
}

// ---------------- cvt combo: z<8192 x->(xh,xT); z<11264 Wqkv->wh;
//                  z<13312 WO row-norms + WO->woh f16; else select_init
__global__ __launch_bounds__(256)
void cvt_combo(const float* __restrict__ x, f16* __restrict__ xh, f16* __restrict__ xT,
               const float* __restrict__ Wqkv, f16* __restrict__ wh,
               const float* __restrict__ WO, float* __restrict__ wno, f16* __restrict__ woh,
               unsigned* __restrict__ hist, unsigned* __restrict__ prefix,
               unsigned* __restrict__ rankrem) {
  const int z = blockIdx.x;
  const int tid = threadIdx.x;
  if (z < 8192) {
    __shared__ f16 t[32][33];
    const int b = z >> 11, r = z & 2047;
    const int s0 = (r & 63) * 32, d0 = (r >> 6) * 32;
    const int tx = tid & 31, ty = tid >> 5;
#pragma unroll
    for (int j = 0; j < 32; j += 8) {
      const long idx = ((long)b * 2048 + s0 + ty + j) * 1024 + d0 + tx;
      f16 h = (f16)x[idx];
      xh[idx] = h;
      t[ty + j][tx] = h;
    }
    __syncthreads();
#pragma unroll
    for (int j = 0; j < 32; j += 8)
      xT[((long)b * 1024 + d0 + ty + j) * 2048 + s0 + tx] = t[tx][ty + j];
  } else if (z < 11264) {
    const long i = (long)(z - 8192) * 256 + tid;
    float4 v = ((const float4*)Wqkv)[i];
    f16x4 o = {(f16)v.x, (f16)v.y, (f16)v.z, (f16)v.w};
    ((f16x4*)wh)[i] = o;
  } else if (z < 13312) {
    const int wid = tid >> 6, lane = tid & 63;
    const long row = (long)(z - 11264) * 4 + wid;
    const float* p = WO + row * 1024;
    float s = 0.f;
#pragma unroll
    for (int j = 0; j < 4; j++) {
      float4 v = *(const float4*)(p + lane * 4 + j * 256);
      s += v.x*v.x + v.y*v.y + v.z*v.z + v.w*v.w;
      f16x4 o = {(f16)v.x, (f16)v.y, (f16)v.z, (f16)v.w};
      *(f16x4*)(woh + row * 1024 + lane * 4 + j * 256) = o;
    }
    for (int off = 32; off; off >>= 1) s += __shfl_down(s, off, 64);
    if (lane == 0) wno[row] = s;
  } else {
    const int i = (z - 13312) * 256 + tid;
    if (i < 12 * 4096) hist[i] = 0;
    if (i < 12) { prefix[i] = 0; rankrem[i] = (i < 8) ? 262144u : 1024u; }
  }
}

// ---------------- radix-select: 2 passes x 4096 bins (bits 31:20, 19:8)
__global__ __launch_bounds__(256)
void hist_pass(const float* __restrict__ nqT, const float* __restrict__ nkT,
               const float* __restrict__ wno, unsigned* __restrict__ hist,
               const unsigned* __restrict__ prefix,
               int shift, int nbins, unsigned himask) {
  __shared__ unsigned lh[4096];
  const int pid = blockIdx.y;
  for (int i = threadIdx.x; i < nbins; i += 256) lh[i] = 0;
  __syncthreads();
  const float* base; long N;
  if (pid < 4)      { base = nqT + (long)pid       * 524288; N = 524288; }
  else if (pid < 8) { base = nkT + (long)(pid - 4) * 524288; N = 524288; }
  else              { base = wno + (long)(pid - 8) * 2048;   N = 2048;  }
  const unsigned pref = prefix[pid];
  long chunk = (N + gridDim.x - 1) / gridDim.x;
  long s = (long)blockIdx.x * chunk;
  long e = s + chunk; if (e > N) e = N;
  for (long i = s + threadIdx.x; i < e; i += 256) {
    unsigned u = __float_as_uint(base[i]);
    if ((u & himask) == pref) atomicAdd(&lh[(u >> shift) & (nbins - 1)], 1u);
  }
  __syncthreads();
  for (int i = threadIdx.x; i < nbins; i += 256)
    if (lh[i]) atomicAdd(&hist[pid * 4096 + i], lh[i]);
}

__global__ __launch_bounds__(256)
void scan_pass(unsigned* __restrict__ hist, unsigned* __restrict__ prefix,
               unsigned* __restrict__ rankrem, float* __restrict__ thr,
               int shift, int nbins, int final_pass) {
  __shared__ unsigned buf[2][256];
  const int pid = blockIdx.x;
  const int tid = threadIdx.x;
  unsigned* h = hist + pid * 4096;
  const int per = nbins >> 8;
  const unsigned r = rankrem[pid];
  const unsigned oldpref = prefix[pid];
  unsigned local[16];
  unsigned s = 0;
#pragma unroll
  for (int j = 0; j < 16; j++) {
    if (j < per) {
      local[j] = h[tid * per + j];
      h[tid * per + j] = 0;
      s += local[j];
    }
  }
  buf[0][tid] = s;
  __syncthreads();
  int src = 0;
#pragma unroll
  for (int d = 1; d < 256; d <<= 1) {
    unsigned v = buf[src][tid];
    if (tid >= d) v += buf[src][tid - d];
    buf[src ^ 1][tid] = v;
    __syncthreads();
    src ^= 1;
  }
  const unsigned incl = buf[src][tid];
  const unsigned excl = incl - s;
  if (excl <= r && r < incl) {
    unsigned accu = excl;
#pragma unroll
    for (int j = 0; j < 16; j++) {
      if (j < per) {
        if (accu + local[j] > r) {
          rankrem[pid] = r - accu;
          unsigned np = oldpref | ((unsigned)(tid * per + j) << shift);
          prefix[pid] = np;
          if (final_pass) thr[pid] = __uint_as_float(np);
          break;
        }
        accu += local[j];
      }
    }
  }
}

// ---------------- mask combo: z<8192 in-place q/k zeroing; else WOT from woh (f16)
__global__ __launch_bounds__(256)
void mask_combo(f16* __restrict__ qkvT, const float* __restrict__ nqT,
                const float* __restrict__ nkT, const float* __restrict__ thr,
                const f16* __restrict__ woh, const float* __restrict__ wno,
                f16* __restrict__ WOT) {
  const int z = blockIdx.x;
  const int tid = threadIdx.x;
  if (z < 8192) {
    const int d  = z & 1023;
    const int tau = (z >> 10) & 1;
    const int bI = z >> 11;
    const float t = thr[tau * 4 + bI];
    const float4 nv = *(const float4*)((tau ? nkT : nqT)
                       + ((long)bI * 512 + (d >> 1)) * 1024 + tid * 4);
    unsigned* pb = (unsigned*)(qkvT + ((long)bI * 3072 + tau * 1024 + d) * 2048 + tid * 8);
    if (nv.x < t) pb[0] = 0u;
    if (nv.y < t) pb[1] = 0u;
    if (nv.z < t) pb[2] = 0u;
    if (nv.w < t) pb[3] = 0u;
  } else {
    __shared__ f16 t[32][33];
    const int zz = z - 8192;
    const int b = zz >> 11, r = zz & 2047;
    const int s0 = (r & 63) * 32, d0 = (r >> 6) * 32;
    const int tx = tid & 31, ty = tid >> 5;
    const float tb = thr[8 + b];
#pragma unroll
    for (int j = 0; j < 32; j += 8) {
      const int s = s0 + ty + j;
      const bool keep = wno[(long)b * 2048 + s] >= tb;
      t[ty + j][tx] = keep ? woh[((long)b * 2048 + s) * 1024 + d0 + tx] : (f16)0.f;
    }
    __syncthreads();
#pragma unroll
    for (int j = 0; j < 32; j += 8)
      WOT[((long)b * 1024 + d0 + ty + j) * 2048 + s0 + tx] = t[tx][ty + j];
  }
}

extern "C" void kernel_launch(void* const* d_in, const int* in_sizes, int n_in,
                              void* d_out, int out_size, void* d_ws, size_t ws_size,
                              hipStream_t stream) {
  const float* x    = (const float*)d_in[0];
  const float* Wqkv = (const float*)d_in[1];
  const float* bqkv = (const float*)d_in[2];
  const float* WO   = (const float*)d_in[3];
  float* out = (float*)d_out;

  char* w = (char*)d_ws;
  auto alloc = [&](size_t bytes) { char* p = w; w += (bytes + 255) & ~(size_t)255; return p; };
  f16*      xh      = (f16*)alloc(8192L * 1024 * 2);
  f16*      wh      = (f16*)alloc(3072L * 1024 * 2);
  f16*      xT      = (f16*)alloc(4L * 1024 * 2048 * 2);
  f16*      qkvT    = (f16*)alloc(4L * 3072 * 2048 * 2);
  float*    nqT     = (float*)alloc(4L * 524288 * 4);
  float*    nkT     = (float*)alloc(4L * 524288 * 4);
  float*    wno     = (float*)alloc(8192L * 4);
  f16*      woh     = (f16*)alloc(8192L * 1024 * 2);
  unsigned* hist    = (unsigned*)alloc(12L * 4096 * 4);
  unsigned* prefix  = (unsigned*)alloc(256);
  unsigned* rankrem = (unsigned*)alloc(256);
  float*    thr     = (float*)alloc(256);
  f16*      WOT     = (f16*)alloc(4L * 1024 * 2048 * 2);
  f16*      B2n     = (f16*)alloc(4L * 1024 * 1024 * 2);
  f16*      Zt      = (f16*)alloc(4L * 1024 * 1024 * 2);
  f16*      A1      = (f16*)alloc(4L * 1024 * 1024 * 2);
  f16*      PT      = (f16*)alloc(4L * 1024 * 1024 * 2);
  f16*      M2T     = (f16*)alloc(4L * 1024 * 1024 * 2);
  if ((size_t)(w - (char*)d_ws) > ws_size) return;

  // 1. conversions + WO norms/f16 + select-init
  cvt_combo<<<13504, 256, 0, stream>>>(x, xh, xT, Wqkv, wh, WO, wno, woh,
                                       hist, prefix, rankrem);
  // 2. qkv GEMM (frozen body) -> qkvT + LDS-staged d-major tile-norms (padded)
  gemm256_qkv<<<512, 512, 0, stream>>>(xh, wh, qkvT, bqkv, nqT, nkT);
  // 3. medians via 2-pass radix select (4 launches: simple, measured-fast)
  hist_pass<<<dim3(32, 12), 256, 0, stream>>>(nqT, nkT, wno, hist, prefix, 20, 4096, 0u);
  scan_pass<<<12, 256, 0, stream>>>(hist, prefix, rankrem, thr, 20, 4096, 0);
  hist_pass<<<dim3(32, 12), 256, 0, stream>>>(nqT, nkT, wno, hist, prefix, 8, 4096, 0xFFF00000u);
  scan_pass<<<12, 256, 0, stream>>>(hist, prefix, rankrem, thr, 8, 4096, 1);
  // 4. masks: in-place q/k zeroing + WOT from f16 woh
  mask_combo<<<16384, 256, 0, stream>>>(qkvT, nqT, nkT, thr, woh, wno, WOT);
  // 5. chain (best-measured assignment, fully XCD-swizzled)
  gemmL1<<<512, 256, 0, stream>>>(xT, qkvT, WOT, B2n, Zt);
  gemmL2<<<512, 256, 0, stream>>>(qkvT, A1, B2n, Zt, PT);
  gemmL3<<<256, 256, 0, stream>>>(A1, PT, M2T);
  gemmL4<<<512, 256, 0, stream>>>(xh, M2T, out);
}